// Round 1
// baseline (993.582 us; speedup 1.0000x reference)
//
#include <hip/hip_runtime.h>
#include <math.h>

#define B_   8
#define S_   1024
#define NXc  768
#define H_   12
#define HDc  64
#define M_   (B_*S_)        // 8192
#define NQKV (3*NXc)        // 2304

// ---- workspace layout (floats) ----
static const size_t WQA_OFF = 0;
static const size_t WQA_CNT = (size_t)NXc * NQKV;      // 1769472
static const size_t WQP_OFF = WQA_OFF + WQA_CNT;
static const size_t WQP_CNT = (size_t)NXc * NXc;       // 589824
static const size_t QQ_OFF  = WQP_OFF + WQP_CNT;
static const size_t QQ_CNT  = (size_t)M_ * NXc;        // 6291456
static const size_t AWS_OFF = QQ_OFF + QQ_CNT;
static const size_t AWS_CNT = (size_t)M_ * NXc;        // 6291456
static const size_t SC_OFF  = AWS_OFF + AWS_CNT;       // 2 uint scalars
static const size_t WS_FLOATS_NEEDED = SC_OFF + 2;

// ---------------- max |tanh(w)| reduction ----------------
__global__ void k_maxtanh(const float* __restrict__ w, int n,
                          unsigned int* __restrict__ out) {
  float mx = 0.f;
  for (int i = blockIdx.x * blockDim.x + threadIdx.x; i < n;
       i += gridDim.x * blockDim.x)
    mx = fmaxf(mx, fabsf(tanhf(w[i])));
#pragma unroll
  for (int off = 32; off > 0; off >>= 1)
    mx = fmaxf(mx, __shfl_xor(mx, off));
  if ((threadIdx.x & 63) == 0)
    atomicMax(out, __float_as_uint(mx));   // floats >= 0: uint order == float order
}

// ---------------- DoReFa weight quant ----------------
__global__ void k_quantw(const float* __restrict__ w, float* __restrict__ wq,
                         int n, const unsigned int* __restrict__ gmax_bits) {
  float gmax = __uint_as_float(*gmax_bits);
  int i = blockIdx.x * blockDim.x + threadIdx.x;
  if (i < n) {
    float t = tanhf(w[i]) / (2.0f * gmax) + 0.5f;
    wq[i] = 2.0f * (rintf(t * 255.0f) / 255.0f) - 1.0f;
  }
}

// ---------------- fp32 GEMM: C = A[MxK] * B[KxN] + bias ----------------
// EPI 0: plain write to Cplain.  EPI 1: act-quant + scatter to qq / kq / vq.
#define BM 128
#define BN 128
#define BK 16

template <int EPI>
__global__ __launch_bounds__(256) void k_gemm(
    const float* __restrict__ A, const float* __restrict__ Bw,
    const float* __restrict__ bias, float* __restrict__ Cplain,
    float* __restrict__ qq, float* __restrict__ kq, float* __restrict__ vq,
    int M, int N, int K) {
  __shared__ float As[BK][BM + 4];
  __shared__ float Bs[BK][BN + 4];
  const int t  = threadIdx.x;
  const int bm = blockIdx.y, bn = blockIdx.x;
  const int tx = t & 15, ty = t >> 4;

  float acc[8][8];
#pragma unroll
  for (int i = 0; i < 8; ++i)
#pragma unroll
    for (int j = 0; j < 8; ++j) acc[i][j] = 0.f;

  const float* Ab = A + (size_t)bm * BM * K;
  const float* Bb = Bw + (size_t)bn * BN;
  const int arow = t >> 2;          // 0..63
  const int acol = (t & 3) * 4;     // 0,4,8,12
  const int brow = t >> 5;          // 0..7
  const int bcol = (t & 31) * 4;    // 0..124

  for (int k0 = 0; k0 < K; k0 += BK) {
#pragma unroll
    for (int rr = 0; rr < 2; ++rr) {
      int r = arow + rr * 64;
      float4 v = *(const float4*)(Ab + (size_t)r * K + k0 + acol);
      As[acol + 0][r] = v.x; As[acol + 1][r] = v.y;
      As[acol + 2][r] = v.z; As[acol + 3][r] = v.w;
    }
#pragma unroll
    for (int rr = 0; rr < 2; ++rr) {
      int kk = brow + rr * 8;
      float4 v = *(const float4*)(Bb + (size_t)(k0 + kk) * N + bcol);
      *(float4*)&Bs[kk][bcol] = v;
    }
    __syncthreads();
#pragma unroll
    for (int kk = 0; kk < BK; ++kk) {
      float a[8], b[8];
      *(float4*)&a[0] = *(const float4*)&As[kk][ty * 8];
      *(float4*)&a[4] = *(const float4*)&As[kk][ty * 8 + 4];
      *(float4*)&b[0] = *(const float4*)&Bs[kk][tx * 8];
      *(float4*)&b[4] = *(const float4*)&Bs[kk][tx * 8 + 4];
#pragma unroll
      for (int i = 0; i < 8; ++i)
#pragma unroll
        for (int j = 0; j < 8; ++j) acc[i][j] += a[i] * b[j];
    }
    __syncthreads();
  }

  const int row0 = bm * BM + ty * 8;
  const int col0 = bn * BN + tx * 8;
#pragma unroll
  for (int i = 0; i < 8; ++i) {
#pragma unroll
    for (int j = 0; j < 8; ++j) {
      float x = acc[i][j] + bias[col0 + j];
      if (EPI == 0) {
        Cplain[(size_t)(row0 + i) * N + col0 + j] = x;
      } else {
        int f = col0 + j;
        int part = f / NXc;
        int ff = f - part * NXc;
        int h = ff >> 6, d = ff & 63;
        int row = row0 + i;
        int b = row >> 10, s = row & 1023;
        float y = rintf(fminf(fmaxf(x, 0.f), 1.f) * 255.0f) / 255.0f;
        size_t dst = (((size_t)b * H_ + h) * S_ + s) * HDc + d;
        float* p = (part == 0) ? qq : (part == 1) ? kq : vq;
        p[dst] = y;
      }
    }
  }
}

// ---------------- causal flash attention (fp32) ----------------
// grid: (16 q-blocks, H, B), 256 threads. q,k,v in [B,H,S,64].
__global__ __launch_bounds__(256) void k_attn(
    const float* __restrict__ qq, const float* __restrict__ kq,
    const float* __restrict__ vq, float* __restrict__ aout) {
  __shared__ float Qs[64][68];
  __shared__ float KPs[64][68];   // K tile, later reused for P
  __shared__ float Vs[64][68];

  const int iq = blockIdx.x, h = blockIdx.y, b = blockIdx.z;
  const size_t hoff = ((size_t)(b * H_ + h)) * S_ * HDc;
  const float* qh = qq + hoff;
  const float* kh = kq + hoff;
  const float* vh = vq + hoff;
  const int t = threadIdx.x;
  const int tx = t & 15, ty = t >> 4;

  // stage Q block once
  for (int i = t; i < 1024; i += 256) {
    int r = i >> 4, c4 = (i & 15) << 2;
    *(float4*)&Qs[r][c4] = *(const float4*)(qh + (size_t)(iq * 64 + r) * HDc + c4);
  }

  float m[4], l[4], o[4][4];
#pragma unroll
  for (int ri = 0; ri < 4; ++ri) {
    m[ri] = -1e30f; l[ri] = 0.f;
#pragma unroll
    for (int di = 0; di < 4; ++di) o[ri][di] = 0.f;
  }

  for (int jb = 0; jb <= iq; ++jb) {
    __syncthreads();  // prev PV reads done (also covers Q staging on iter 0)
    for (int i = t; i < 1024; i += 256) {
      int r = i >> 4, c4 = (i & 15) << 2;
      int cs = (c4 + (((r >> 2) & 15) << 2)) & 63;   // XOR/rotate swizzle for K
      *(float4*)&KPs[r][cs] = *(const float4*)(kh + (size_t)(jb * 64 + r) * HDc + c4);
      *(float4*)&Vs[r][c4]  = *(const float4*)(vh + (size_t)(jb * 64 + r) * HDc + c4);
    }
    __syncthreads();

    // QK^T: s[ri][ji] = q(row ty*4+ri) . k(row tx*4+ji)
    float s[4][4];
#pragma unroll
    for (int ri = 0; ri < 4; ++ri)
#pragma unroll
      for (int ji = 0; ji < 4; ++ji) s[ri][ji] = 0.f;
#pragma unroll
    for (int d4 = 0; d4 < 16; ++d4) {
      float qa[4][4], ka[4][4];
      int qc = d4 << 2;
      int kc = ((d4 + tx) & 15) << 2;   // matches store-side swizzle (row>>2 == tx)
#pragma unroll
      for (int ri = 0; ri < 4; ++ri)
        *(float4*)&qa[ri][0] = *(const float4*)&Qs[ty * 4 + ri][qc];
#pragma unroll
      for (int ji = 0; ji < 4; ++ji)
        *(float4*)&ka[ji][0] = *(const float4*)&KPs[tx * 4 + ji][kc];
#pragma unroll
      for (int ri = 0; ri < 4; ++ri)
#pragma unroll
        for (int ji = 0; ji < 4; ++ji)
#pragma unroll
          for (int dd = 0; dd < 4; ++dd)
            s[ri][ji] += qa[ri][dd] * ka[ji][dd];
    }

    // online softmax (rows owned by 16 lanes sharing ty)
    const int grow = iq * 64 + ty * 4;
    const int gcol = jb * 64 + tx * 4;
    float mt[4];
#pragma unroll
    for (int ri = 0; ri < 4; ++ri) {
      float mx = -1e30f;
#pragma unroll
      for (int ji = 0; ji < 4; ++ji) {
        float xx = s[ri][ji] * 0.125f;
        if (jb == iq && (gcol + ji) > (grow + ri)) xx = -1e30f;
        s[ri][ji] = xx;
        mx = fmaxf(mx, xx);
      }
      mt[ri] = mx;
    }
#pragma unroll
    for (int off = 1; off < 16; off <<= 1)
#pragma unroll
      for (int ri = 0; ri < 4; ++ri)
        mt[ri] = fmaxf(mt[ri], __shfl_xor(mt[ri], off));

    float rs[4];
#pragma unroll
    for (int ri = 0; ri < 4; ++ri) {
      float mn = fmaxf(m[ri], mt[ri]);
      float sc = __expf(m[ri] - mn);
      m[ri] = mn;
      l[ri] *= sc;
#pragma unroll
      for (int di = 0; di < 4; ++di) o[ri][di] *= sc;
      float sum = 0.f;
#pragma unroll
      for (int ji = 0; ji < 4; ++ji) {
        float p = __expf(s[ri][ji] - mn);
        s[ri][ji] = p;
        sum += p;
      }
      rs[ri] = sum;
    }
#pragma unroll
    for (int off = 1; off < 16; off <<= 1)
#pragma unroll
      for (int ri = 0; ri < 4; ++ri) rs[ri] += __shfl_xor(rs[ri], off);
#pragma unroll
    for (int ri = 0; ri < 4; ++ri) l[ri] += rs[ri];

    __syncthreads();  // K reads finished -> reuse KPs for P
#pragma unroll
    for (int ri = 0; ri < 4; ++ri)
      *(float4*)&KPs[ty * 4 + ri][tx * 4] =
          make_float4(s[ri][0], s[ri][1], s[ri][2], s[ri][3]);
    __syncthreads();

    // PV: o[ri][di] += sum_j P[row][j] * V[j][tx*4+di]
#pragma unroll
    for (int j4 = 0; j4 < 16; ++j4) {
      float p4a[4][4];
#pragma unroll
      for (int ri = 0; ri < 4; ++ri)
        *(float4*)&p4a[ri][0] = *(const float4*)&KPs[ty * 4 + ri][j4 << 2];
#pragma unroll
      for (int jj = 0; jj < 4; ++jj) {
        float4 vv = *(const float4*)&Vs[(j4 << 2) + jj][tx * 4];
#pragma unroll
        for (int ri = 0; ri < 4; ++ri) {
          float p = p4a[ri][jj];
          o[ri][0] += p * vv.x; o[ri][1] += p * vv.y;
          o[ri][2] += p * vv.z; o[ri][3] += p * vv.w;
        }
      }
    }
  }

  // write merged-head layout [B,S,NX]
#pragma unroll
  for (int ri = 0; ri < 4; ++ri) {
    float inv = 1.0f / l[ri];
    size_t row = (size_t)b * S_ + iq * 64 + ty * 4 + ri;
    *(float4*)(aout + row * NXc + h * HDc + tx * 4) =
        make_float4(o[ri][0] * inv, o[ri][1] * inv, o[ri][2] * inv, o[ri][3] * inv);
  }
}

// ---------------- host launcher ----------------
extern "C" void kernel_launch(void* const* d_in, const int* in_sizes, int n_in,
                              void* d_out, int out_size, void* d_ws, size_t ws_size,
                              hipStream_t stream) {
  const float* x      = (const float*)d_in[0];
  const float* W_attn = (const float*)d_in[1];
  const float* b_attn = (const float*)d_in[2];
  const float* W_proj = (const float*)d_in[3];
  const float* b_proj = (const float*)d_in[4];

  float* out = (float*)d_out;
  float* ws  = (float*)d_ws;
  if (ws_size < WS_FLOATS_NEEDED * sizeof(float)) return;  // fail loud (zeros)

  float* a_out = out;                               // [B,S,NX]
  float* k_out = out + (size_t)M_ * NXc;            // present[0] = k  [B,H,S,hd]
  float* v_out = k_out + (size_t)M_ * NXc;          // present[1] = v

  float* wqa  = ws + WQA_OFF;
  float* wqp  = ws + WQP_OFF;
  float* qqw  = ws + QQ_OFF;
  float* awsp = ws + AWS_OFF;
  unsigned int* sc = (unsigned int*)(ws + SC_OFF);

  hipMemsetAsync(sc, 0, 2 * sizeof(unsigned int), stream);

  k_maxtanh<<<256, 256, 0, stream>>>(W_attn, NXc * NQKV, sc);
  k_maxtanh<<<256, 256, 0, stream>>>(W_proj, NXc * NXc, sc + 1);

  k_quantw<<<(NXc * NQKV + 255) / 256, 256, 0, stream>>>(W_attn, wqa, NXc * NQKV, sc);
  k_quantw<<<(NXc * NXc + 255) / 256, 256, 0, stream>>>(W_proj, wqp, NXc * NXc, sc + 1);

  // qkv = x @ Wq_attn + b_attn, fused act-quant + head-split scatter
  k_gemm<1><<<dim3(NQKV / BN, M_ / BM), 256, 0, stream>>>(
      x, wqa, b_attn, nullptr, qqw, k_out, v_out, M_, NQKV, NXc);

  // causal attention
  k_attn<<<dim3(S_ / 64, H_, B_), 256, 0, stream>>>(qqw, k_out, v_out, awsp);

  // a = attn_out @ Wq_proj + b_proj
  k_gemm<0><<<dim3(NXc / BN, M_ / BM), 256, 0, stream>>>(
      awsp, wqp, b_proj, a_out, nullptr, nullptr, nullptr, M_, NXc, NXc);
}

// Round 2
// 627.586 us; speedup vs baseline: 1.5832x; 1.5832x over previous
//
#include <hip/hip_runtime.h>
#include <math.h>

#define B_   8
#define S_   1024
#define NXc  768
#define H_   12
#define HDc  64
#define M_   (B_*S_)        // 8192
#define NQKV (3*NXc)        // 2304

typedef __attribute__((ext_vector_type(8))) short short8;
typedef __attribute__((ext_vector_type(4))) float f32x4;

__device__ inline unsigned short f2bf(float f) {
  unsigned u = __float_as_uint(f);
  return (unsigned short)((u + 0x7fffu + ((u >> 16) & 1u)) >> 16);
}
__device__ inline float bf2f(unsigned short h) {
  return __uint_as_float(((unsigned)h) << 16);
}

// ---- workspace layout ----
// bf16 (u16) regions first, then fp32 regions, then scalars. All counted in floats.
static const size_t UA_OFF_F  = 0;                                   // u16 count NQKV*NXc
static const size_t UA_F_CNT  = ((size_t)NQKV * NXc + 1) / 2;        // 884736 floats
static const size_t UP_OFF_F  = UA_OFF_F + UA_F_CNT;
static const size_t UP_F_CNT  = ((size_t)NXc * NXc + 1) / 2;         // 294912
static const size_t QQ_OFF    = UP_OFF_F + UP_F_CNT;
static const size_t QQ_CNT    = (size_t)M_ * NXc;                    // 6291456
static const size_t AWS_OFF   = QQ_OFF + QQ_CNT;
static const size_t AWS_CNT   = (size_t)M_ * NXc;                    // 6291456
static const size_t SC_OFF    = AWS_OFF + AWS_CNT;
static const size_t WS_FLOATS_NEEDED = SC_OFF + 2;

// ---------------- max |tanh(w)| reduction ----------------
__global__ void k_maxtanh(const float* __restrict__ w, int n,
                          unsigned int* __restrict__ out) {
  float mx = 0.f;
  for (int i = blockIdx.x * blockDim.x + threadIdx.x; i < n;
       i += gridDim.x * blockDim.x)
    mx = fmaxf(mx, fabsf(tanhf(w[i])));
#pragma unroll
  for (int off = 32; off > 0; off >>= 1)
    mx = fmaxf(mx, __shfl_xor(mx, off));
  if ((threadIdx.x & 63) == 0)
    atomicMax(out, __float_as_uint(mx));   // floats >= 0: uint order == float order
}

// ---------------- DoReFa weight quant -> transposed exact-bf16 integer weights ----
// Ut[n][k] = 2*round(t*255) - 255, t = tanh(w[k][n])/(2*gmax)+0.5. |u|<=255 odd -> exact bf16.
__global__ __launch_bounds__(256) void k_quantw_t(
    const float* __restrict__ w, unsigned short* __restrict__ ut,
    int K, int N, const unsigned int* __restrict__ gmax_bits) {
  __shared__ unsigned short Ut[64][72];
  const float inv2m = 0.5f / __uint_as_float(*gmax_bits);
  const int k0 = blockIdx.y * 64, n0 = blockIdx.x * 64;
  const int t = threadIdx.x;
  const int r = t >> 4, c4 = (t & 15) * 4;
#pragma unroll
  for (int rr = 0; rr < 4; ++rr) {
    int row = rr * 16 + r;
    float4 f = *(const float4*)(w + (size_t)(k0 + row) * N + n0 + c4);
    float fv[4] = {f.x, f.y, f.z, f.w};
#pragma unroll
    for (int j = 0; j < 4; ++j) {
      float tq = tanhf(fv[j]) * inv2m + 0.5f;
      float u = 2.0f * rintf(tq * 255.0f) - 255.0f;
      Ut[c4 + j][row] = f2bf(u);
    }
  }
  __syncthreads();
#pragma unroll
  for (int rep = 0; rep < 2; ++rep) {
    int c = t + rep * 256;
    int n = c >> 3, slot = c & 7;
    short8 v = *(const short8*)&Ut[n][slot * 8];
    *(short8*)(ut + (size_t)(n0 + n) * K + k0 + slot * 8) = v;
  }
}

// ---------------- MFMA GEMM: C = (A * U^T)/255 + bias ----------------
// A fp32 [M][K] split on the fly into hi/lo bf16 (fp32-exact to ~2^-16 rel).
// Ut bf16 [N][K] exact integer weights. 128x128 tile, BK=32, 4 waves of 64x64.
// EPI 0: plain fp32 store. EPI 1: act-quant + head-split scatter (qkv path).
template <int EPI>
__global__ __launch_bounds__(256) void k_gemm_mfma(
    const float* __restrict__ A, const unsigned short* __restrict__ Ut,
    const float* __restrict__ bias, float* __restrict__ Cplain,
    float* __restrict__ qq, float* __restrict__ kq, float* __restrict__ vq,
    int M, int N, int K) {
  // 16B entries, slot-major: entry[slot][row], slot = (k - k0)/8
  __shared__ short8 Ahi[4 * 128];
  __shared__ short8 Alo[4 * 128];
  __shared__ short8 Bsm[4 * 128];

  const int t = threadIdx.x;
  const int bm = blockIdx.y, bn = blockIdx.x;
  const int wave = t >> 6, lane = t & 63;
  const int wm = wave >> 1, wn = wave & 1;     // 2x2 waves -> 64x64 each
  const int g = lane >> 4, ln = lane & 15;

  const float* Ab = A + (size_t)bm * 128 * K;
  const unsigned short* Bb = Ut + (size_t)bn * 128 * K;

  f32x4 acc[4][4];
#pragma unroll
  for (int i = 0; i < 4; ++i)
#pragma unroll
    for (int j = 0; j < 4; ++j) acc[i][j] = (f32x4)(0.f);

  for (int k0 = 0; k0 < K; k0 += 32) {
    __syncthreads();   // previous compute's LDS reads done
#pragma unroll
    for (int rep = 0; rep < 2; ++rep) {
      int e = t + rep * 256;
      int slot = e & 3, m = e >> 2;
      const float* src = Ab + (size_t)m * K + k0 + slot * 8;
      float4 f0 = *(const float4*)(src);
      float4 f1 = *(const float4*)(src + 4);
      float fv[8] = {f0.x, f0.y, f0.z, f0.w, f1.x, f1.y, f1.z, f1.w};
      union { short8 v; unsigned short u[8]; } hi, lo;
#pragma unroll
      for (int j = 0; j < 8; ++j) {
        unsigned short h = f2bf(fv[j]);
        hi.u[j] = h;
        lo.u[j] = f2bf(fv[j] - bf2f(h));
      }
      Ahi[slot * 128 + m] = hi.v;
      Alo[slot * 128 + m] = lo.v;
    }
#pragma unroll
    for (int rep = 0; rep < 2; ++rep) {
      int e = t + rep * 256;
      int slot = e & 3, n = e >> 2;
      Bsm[slot * 128 + n] = *(const short8*)(Bb + (size_t)n * K + k0 + slot * 8);
    }
    __syncthreads();

    short8 bfrag[4];
#pragma unroll
    for (int nf = 0; nf < 4; ++nf)
      bfrag[nf] = Bsm[g * 128 + wn * 64 + nf * 16 + ln];
#pragma unroll
    for (int mf = 0; mf < 4; ++mf) {
      short8 ah = Ahi[g * 128 + wm * 64 + mf * 16 + ln];
      short8 al = Alo[g * 128 + wm * 64 + mf * 16 + ln];
#pragma unroll
      for (int nf = 0; nf < 4; ++nf) {
        acc[mf][nf] = __builtin_amdgcn_mfma_f32_16x16x32_bf16(ah, bfrag[nf], acc[mf][nf], 0, 0, 0);
        acc[mf][nf] = __builtin_amdgcn_mfma_f32_16x16x32_bf16(al, bfrag[nf], acc[mf][nf], 0, 0, 0);
      }
    }
  }

  const float inv255 = 1.0f / 255.0f;
#pragma unroll
  for (int mf = 0; mf < 4; ++mf) {
    int row0 = bm * 128 + wm * 64 + mf * 16 + g * 4;
#pragma unroll
    for (int nf = 0; nf < 4; ++nf) {
      int col = bn * 128 + wn * 64 + nf * 16 + ln;
      float bv = bias[col];
#pragma unroll
      for (int r = 0; r < 4; ++r) {
        float x = acc[mf][nf][r] * inv255 + bv;
        int row = row0 + r;
        if (EPI == 0) {
          Cplain[(size_t)row * N + col] = x;
        } else {
          int part = col / NXc;
          int ff = col - part * NXc;
          int h = ff >> 6, d = ff & 63;
          int b = row >> 10, s = row & 1023;
          float y = rintf(fminf(fmaxf(x, 0.f), 1.f) * 255.0f) * inv255;
          size_t dst = (((size_t)b * H_ + h) * S_ + s) * HDc + d;
          float* p = (part == 0) ? qq : (part == 1) ? kq : vq;
          p[dst] = y;
        }
      }
    }
  }
}

// ---------------- causal flash attention (fp32) ----------------
// grid: (16 q-blocks, H, B), 256 threads. q,k,v in [B,H,S,64].
__global__ __launch_bounds__(256) void k_attn(
    const float* __restrict__ qq, const float* __restrict__ kq,
    const float* __restrict__ vq, float* __restrict__ aout) {
  __shared__ float Qs[64][68];
  __shared__ float KPs[64][68];   // K tile, later reused for P
  __shared__ float Vs[64][68];

  const int iq = (gridDim.x - 1) - blockIdx.x;   // long blocks dispatch first
  const int h = blockIdx.y, b = blockIdx.z;
  const size_t hoff = ((size_t)(b * H_ + h)) * S_ * HDc;
  const float* qh = qq + hoff;
  const float* kh = kq + hoff;
  const float* vh = vq + hoff;
  const int t = threadIdx.x;
  const int tx = t & 15, ty = t >> 4;

  for (int i = t; i < 1024; i += 256) {
    int r = i >> 4, c4 = (i & 15) << 2;
    *(float4*)&Qs[r][c4] = *(const float4*)(qh + (size_t)(iq * 64 + r) * HDc + c4);
  }

  float m[4], l[4], o[4][4];
#pragma unroll
  for (int ri = 0; ri < 4; ++ri) {
    m[ri] = -1e30f; l[ri] = 0.f;
#pragma unroll
    for (int di = 0; di < 4; ++di) o[ri][di] = 0.f;
  }

  for (int jb = 0; jb <= iq; ++jb) {
    __syncthreads();
    for (int i = t; i < 1024; i += 256) {
      int r = i >> 4, c4 = (i & 15) << 2;
      int cs = (c4 + (((r >> 2) & 15) << 2)) & 63;   // rotate swizzle for K
      *(float4*)&KPs[r][cs] = *(const float4*)(kh + (size_t)(jb * 64 + r) * HDc + c4);
      *(float4*)&Vs[r][c4]  = *(const float4*)(vh + (size_t)(jb * 64 + r) * HDc + c4);
    }
    __syncthreads();

    float s[4][4];
#pragma unroll
    for (int ri = 0; ri < 4; ++ri)
#pragma unroll
      for (int ji = 0; ji < 4; ++ji) s[ri][ji] = 0.f;
#pragma unroll
    for (int d4 = 0; d4 < 16; ++d4) {
      float qa[4][4], ka[4][4];
      int qc = d4 << 2;
      int kc = ((d4 + tx) & 15) << 2;
#pragma unroll
      for (int ri = 0; ri < 4; ++ri)
        *(float4*)&qa[ri][0] = *(const float4*)&Qs[ty * 4 + ri][qc];
#pragma unroll
      for (int ji = 0; ji < 4; ++ji)
        *(float4*)&ka[ji][0] = *(const float4*)&KPs[tx * 4 + ji][kc];
#pragma unroll
      for (int ri = 0; ri < 4; ++ri)
#pragma unroll
        for (int ji = 0; ji < 4; ++ji)
#pragma unroll
          for (int dd = 0; dd < 4; ++dd)
            s[ri][ji] += qa[ri][dd] * ka[ji][dd];
    }

    const int grow = iq * 64 + ty * 4;
    const int gcol = jb * 64 + tx * 4;
    float mt[4];
#pragma unroll
    for (int ri = 0; ri < 4; ++ri) {
      float mx = -1e30f;
#pragma unroll
      for (int ji = 0; ji < 4; ++ji) {
        float xx = s[ri][ji] * 0.125f;
        if (jb == iq && (gcol + ji) > (grow + ri)) xx = -1e30f;
        s[ri][ji] = xx;
        mx = fmaxf(mx, xx);
      }
      mt[ri] = mx;
    }
#pragma unroll
    for (int off = 1; off < 16; off <<= 1)
#pragma unroll
      for (int ri = 0; ri < 4; ++ri)
        mt[ri] = fmaxf(mt[ri], __shfl_xor(mt[ri], off));

    float rs[4];
#pragma unroll
    for (int ri = 0; ri < 4; ++ri) {
      float mn = fmaxf(m[ri], mt[ri]);
      float sc = __expf(m[ri] - mn);
      m[ri] = mn;
      l[ri] *= sc;
#pragma unroll
      for (int di = 0; di < 4; ++di) o[ri][di] *= sc;
      float sum = 0.f;
#pragma unroll
      for (int ji = 0; ji < 4; ++ji) {
        float p = __expf(s[ri][ji] - mn);
        s[ri][ji] = p;
        sum += p;
      }
      rs[ri] = sum;
    }
#pragma unroll
    for (int off = 1; off < 16; off <<= 1)
#pragma unroll
      for (int ri = 0; ri < 4; ++ri) rs[ri] += __shfl_xor(rs[ri], off);
#pragma unroll
    for (int ri = 0; ri < 4; ++ri) l[ri] += rs[ri];

    __syncthreads();
#pragma unroll
    for (int ri = 0; ri < 4; ++ri)
      *(float4*)&KPs[ty * 4 + ri][tx * 4] =
          make_float4(s[ri][0], s[ri][1], s[ri][2], s[ri][3]);
    __syncthreads();

#pragma unroll
    for (int j4 = 0; j4 < 16; ++j4) {
      float p4a[4][4];
#pragma unroll
      for (int ri = 0; ri < 4; ++ri)
        *(float4*)&p4a[ri][0] = *(const float4*)&KPs[ty * 4 + ri][j4 << 2];
#pragma unroll
      for (int jj = 0; jj < 4; ++jj) {
        float4 vv = *(const float4*)&Vs[(j4 << 2) + jj][tx * 4];
#pragma unroll
        for (int ri = 0; ri < 4; ++ri) {
          float p = p4a[ri][jj];
          o[ri][0] += p * vv.x; o[ri][1] += p * vv.y;
          o[ri][2] += p * vv.z; o[ri][3] += p * vv.w;
        }
      }
    }
  }

#pragma unroll
  for (int ri = 0; ri < 4; ++ri) {
    float inv = 1.0f / l[ri];
    size_t row = (size_t)b * S_ + iq * 64 + ty * 4 + ri;
    *(float4*)(aout + row * NXc + h * HDc + tx * 4) =
        make_float4(o[ri][0] * inv, o[ri][1] * inv, o[ri][2] * inv, o[ri][3] * inv);
  }
}

// ---------------- host launcher ----------------
extern "C" void kernel_launch(void* const* d_in, const int* in_sizes, int n_in,
                              void* d_out, int out_size, void* d_ws, size_t ws_size,
                              hipStream_t stream) {
  const float* x      = (const float*)d_in[0];
  const float* W_attn = (const float*)d_in[1];
  const float* b_attn = (const float*)d_in[2];
  const float* W_proj = (const float*)d_in[3];
  const float* b_proj = (const float*)d_in[4];

  float* out = (float*)d_out;
  float* ws  = (float*)d_ws;
  if (ws_size < WS_FLOATS_NEEDED * sizeof(float)) return;

  float* a_out = out;                               // [B,S,NX]
  float* k_out = out + (size_t)M_ * NXc;            // present[0] = k  [B,H,S,hd]
  float* v_out = k_out + (size_t)M_ * NXc;          // present[1] = v

  unsigned short* ua = (unsigned short*)(ws + UA_OFF_F);   // [NQKV][NXc] bf16 u
  unsigned short* up = (unsigned short*)(ws + UP_OFF_F);   // [NXc][NXc]  bf16 u
  float* qqw  = ws + QQ_OFF;
  float* awsp = ws + AWS_OFF;
  unsigned int* sc = (unsigned int*)(ws + SC_OFF);

  hipMemsetAsync(sc, 0, 2 * sizeof(unsigned int), stream);

  k_maxtanh<<<256, 256, 0, stream>>>(W_attn, NXc * NQKV, sc);
  k_maxtanh<<<256, 256, 0, stream>>>(W_proj, NXc * NXc, sc + 1);

  // quant + transpose: Ut[n][k] (exact bf16 integers)
  k_quantw_t<<<dim3(NQKV / 64, NXc / 64), 256, 0, stream>>>(W_attn, ua, NXc, NQKV, sc);
  k_quantw_t<<<dim3(NXc / 64, NXc / 64), 256, 0, stream>>>(W_proj, up, NXc, NXc, sc + 1);

  // qkv = x @ wq_attn + b_attn (MFMA split-bf16), fused act-quant + head-split
  k_gemm_mfma<1><<<dim3(NQKV / 128, M_ / 128), 256, 0, stream>>>(
      x, ua, b_attn, nullptr, qqw, k_out, v_out, M_, NQKV, NXc);

  // causal attention
  k_attn<<<dim3(S_ / 64, H_, B_), 256, 0, stream>>>(qqw, k_out, v_out, awsp);

  // a = attn_out @ wq_proj + b_proj (MFMA split-bf16)
  k_gemm_mfma<0><<<dim3(NXc / 128, M_ / 128), 256, 0, stream>>>(
      awsp, up, b_proj, a_out, nullptr, nullptr, nullptr, M_, NXc, NXc);
}

// Round 3
// 329.220 us; speedup vs baseline: 3.0180x; 1.9063x over previous
//
#include <hip/hip_runtime.h>
#include <math.h>

#define B_   8
#define S_   1024
#define NXc  768
#define H_   12
#define HDc  64
#define M_   (B_*S_)        // 8192
#define NQKV (3*NXc)        // 2304

typedef __attribute__((ext_vector_type(8))) short short8;
typedef __attribute__((ext_vector_type(4))) float f32x4;
typedef unsigned short ushort_t;

__device__ inline unsigned short f2bf(float f) {
  unsigned u = __float_as_uint(f);
  return (unsigned short)((u + 0x7fffu + ((u >> 16) & 1u)) >> 16);
}
__device__ inline float bf2f(unsigned short h) {
  return __uint_as_float(((unsigned)h) << 16);
}

// ---- workspace layout (floats) ----
static const size_t UA_OFF_F  = 0;                                   // bf16 Ut attn
static const size_t UA_F_CNT  = ((size_t)NQKV * NXc + 1) / 2;        // 884736
static const size_t UP_OFF_F  = UA_OFF_F + UA_F_CNT;
static const size_t UP_F_CNT  = ((size_t)NXc * NXc + 1) / 2;         // 294912
static const size_t QBF_OFF_F = UP_OFF_F + UP_F_CNT;                 // bf16 int q [B,H,S,64]
static const size_t QBF_F_CNT = ((size_t)M_ * NXc + 1) / 2;          // 3145728
static const size_t AWS_OFF   = QBF_OFF_F + QBF_F_CNT;               // fp32 attn out [B,S,NX]
static const size_t AWS_CNT   = (size_t)M_ * NXc;                    // 6291456
static const size_t SC_OFF    = AWS_OFF + AWS_CNT;
static const size_t WS_FLOATS_NEEDED = SC_OFF + 2;

// ---------------- max |tanh(w)| reduction ----------------
__global__ void k_maxtanh(const float* __restrict__ w, int n,
                          unsigned int* __restrict__ out) {
  float mx = 0.f;
  for (int i = blockIdx.x * blockDim.x + threadIdx.x; i < n;
       i += gridDim.x * blockDim.x)
    mx = fmaxf(mx, fabsf(tanhf(w[i])));
#pragma unroll
  for (int off = 32; off > 0; off >>= 1)
    mx = fmaxf(mx, __shfl_xor(mx, off));
  if ((threadIdx.x & 63) == 0)
    atomicMax(out, __float_as_uint(mx));
}

// ---------------- DoReFa weight quant -> transposed exact-bf16 integer weights ----
__global__ __launch_bounds__(256) void k_quantw_t(
    const float* __restrict__ w, unsigned short* __restrict__ ut,
    int K, int N, const unsigned int* __restrict__ gmax_bits) {
  __shared__ unsigned short Ut[64][72];
  const float inv2m = 0.5f / __uint_as_float(*gmax_bits);
  const int k0 = blockIdx.y * 64, n0 = blockIdx.x * 64;
  const int t = threadIdx.x;
  const int r = t >> 4, c4 = (t & 15) * 4;
#pragma unroll
  for (int rr = 0; rr < 4; ++rr) {
    int row = rr * 16 + r;
    float4 f = *(const float4*)(w + (size_t)(k0 + row) * N + n0 + c4);
    float fv[4] = {f.x, f.y, f.z, f.w};
#pragma unroll
    for (int j = 0; j < 4; ++j) {
      float tq = tanhf(fv[j]) * inv2m + 0.5f;
      float u = 2.0f * rintf(tq * 255.0f) - 255.0f;
      Ut[c4 + j][row] = f2bf(u);
    }
  }
  __syncthreads();
#pragma unroll
  for (int rep = 0; rep < 2; ++rep) {
    int c = t + rep * 256;
    int n = c >> 3, slot = c & 7;
    short8 v = *(const short8*)&Ut[n][slot * 8];
    *(short8*)(ut + (size_t)(n0 + n) * K + k0 + slot * 8) = v;
  }
}

// ---------------- MFMA GEMM: C = (A * U^T)/255 + bias ----------------
// EPI 0: plain fp32 store. EPI 1: act-quant; q -> bf16 int ws, k/v -> fp32 out.
template <int EPI>
__global__ __launch_bounds__(256) void k_gemm_mfma(
    const float* __restrict__ A, const unsigned short* __restrict__ Ut,
    const float* __restrict__ bias, float* __restrict__ Cplain,
    unsigned short* __restrict__ qbf, float* __restrict__ kq, float* __restrict__ vq,
    int M, int N, int K) {
  __shared__ short8 Ahi[4 * 128];
  __shared__ short8 Alo[4 * 128];
  __shared__ short8 Bsm[4 * 128];

  const int t = threadIdx.x;
  const int bm = blockIdx.y, bn = blockIdx.x;
  const int wave = t >> 6, lane = t & 63;
  const int wm = wave >> 1, wn = wave & 1;
  const int g = lane >> 4, ln = lane & 15;

  const float* Ab = A + (size_t)bm * 128 * K;
  const unsigned short* Bb = Ut + (size_t)bn * 128 * K;

  f32x4 acc[4][4];
#pragma unroll
  for (int i = 0; i < 4; ++i)
#pragma unroll
    for (int j = 0; j < 4; ++j) acc[i][j] = (f32x4)(0.f);

  for (int k0 = 0; k0 < K; k0 += 32) {
    __syncthreads();
#pragma unroll
    for (int rep = 0; rep < 2; ++rep) {
      int e = t + rep * 256;
      int slot = e & 3, m = e >> 2;
      const float* src = Ab + (size_t)m * K + k0 + slot * 8;
      float4 f0 = *(const float4*)(src);
      float4 f1 = *(const float4*)(src + 4);
      float fv[8] = {f0.x, f0.y, f0.z, f0.w, f1.x, f1.y, f1.z, f1.w};
      union { short8 v; unsigned short u[8]; } hi, lo;
#pragma unroll
      for (int j = 0; j < 8; ++j) {
        unsigned short h = f2bf(fv[j]);
        hi.u[j] = h;
        lo.u[j] = f2bf(fv[j] - bf2f(h));
      }
      Ahi[slot * 128 + m] = hi.v;
      Alo[slot * 128 + m] = lo.v;
    }
#pragma unroll
    for (int rep = 0; rep < 2; ++rep) {
      int e = t + rep * 256;
      int slot = e & 3, n = e >> 2;
      Bsm[slot * 128 + n] = *(const short8*)(Bb + (size_t)n * K + k0 + slot * 8);
    }
    __syncthreads();

    short8 bfrag[4];
#pragma unroll
    for (int nf = 0; nf < 4; ++nf)
      bfrag[nf] = Bsm[g * 128 + wn * 64 + nf * 16 + ln];
#pragma unroll
    for (int mf = 0; mf < 4; ++mf) {
      short8 ah = Ahi[g * 128 + wm * 64 + mf * 16 + ln];
      short8 al = Alo[g * 128 + wm * 64 + mf * 16 + ln];
#pragma unroll
      for (int nf = 0; nf < 4; ++nf) {
        acc[mf][nf] = __builtin_amdgcn_mfma_f32_16x16x32_bf16(ah, bfrag[nf], acc[mf][nf], 0, 0, 0);
        acc[mf][nf] = __builtin_amdgcn_mfma_f32_16x16x32_bf16(al, bfrag[nf], acc[mf][nf], 0, 0, 0);
      }
    }
  }

  const float inv255 = 1.0f / 255.0f;
#pragma unroll
  for (int mf = 0; mf < 4; ++mf) {
    int row0 = bm * 128 + wm * 64 + mf * 16 + g * 4;
#pragma unroll
    for (int nf = 0; nf < 4; ++nf) {
      int col = bn * 128 + wn * 64 + nf * 16 + ln;
      float bv = bias[col];
#pragma unroll
      for (int r = 0; r < 4; ++r) {
        float x = acc[mf][nf][r] * inv255 + bv;
        int row = row0 + r;
        if (EPI == 0) {
          Cplain[(size_t)row * N + col] = x;
        } else {
          int part = col / NXc;
          int ff = col - part * NXc;
          int h = ff >> 6, d = ff & 63;
          int b = row >> 10, s = row & 1023;
          float y255 = rintf(fminf(fmaxf(x, 0.f), 1.f) * 255.0f);
          size_t dst = (((size_t)b * H_ + h) * S_ + s) * HDc + d;
          if (part == 0)      qbf[dst] = f2bf(y255);     // exact bf16 integer
          else if (part == 1) kq[dst] = y255 * inv255;
          else                vq[dst] = y255 * inv255;
        }
      }
    }
  }
}

// ---------------- MFMA causal flash attention ----------------
// grid: (16, H, B), 256 threads (4 waves x 16 q-rows). q bf16 int; k,v fp32 (/255).
// QK^T on integer-scaled values is EXACT (sums < 2^23). P split hi/lo bf16 for PV.
__global__ __launch_bounds__(256) void k_attn_mfma(
    const unsigned short* __restrict__ qw, const float* __restrict__ kf,
    const float* __restrict__ vf, float* __restrict__ aout) {
  __shared__ __align__(16) unsigned short Ks[64 * 64];  // [kv][d] ^ ((kv&7)<<3)
  __shared__ __align__(16) unsigned short Vs[64 * 64];  // [kv][d] ^ (((kv>>3)&7)<<3)
  __shared__ __align__(16) unsigned int   Pp[64 * 64];  // [q][kv] (hi,lo) ^ ((q&7)<<3)

  const int iq = (gridDim.x - 1) - blockIdx.x;
  const int h = blockIdx.y, b = blockIdx.z;
  const size_t hoff = ((size_t)(b * H_ + h)) * S_ * HDc;
  const unsigned short* qh = qw + hoff;
  const float* kh = kf + hoff;
  const float* vh = vf + hoff;

  const int t = threadIdx.x;
  const int w = t >> 6, lane = t & 63;
  const int g = lane >> 4, ln = lane & 15;

  // Q fragments (integer-scaled bf16), rows w*16+ln, once per block
  short8 qfrag[2];
  {
    const unsigned short* qr = qh + (size_t)(iq * 64 + w * 16 + ln) * HDc;
#pragma unroll
    for (int ks = 0; ks < 2; ++ks)
      qfrag[ks] = *(const short8*)(qr + ks * 32 + g * 8);
  }

  float m[4], l[4];
  f32x4 accO[4];
#pragma unroll
  for (int r = 0; r < 4; ++r) { m[r] = -1e30f; l[r] = 0.f; }
#pragma unroll
  for (int nf = 0; nf < 4; ++nf) accO[nf] = (f32x4)(0.f);

  const float SCALE = 1.0f / (255.0f * 255.0f * 8.0f);

  for (int jb = 0; jb <= iq; ++jb) {
    __syncthreads();   // previous tile's LDS reads complete
    // stage K,V: fp32 -> exact bf16 integers, swizzled
    for (int idx = t; idx < 512; idx += 256) {
      int row = idx >> 3, slot = idx & 7;
      {
        const float* src = kh + (size_t)(jb * 64 + row) * HDc + slot * 8;
        float4 f0 = *(const float4*)src;
        float4 f1 = *(const float4*)(src + 4);
        float fv[8] = {f0.x, f0.y, f0.z, f0.w, f1.x, f1.y, f1.z, f1.w};
        union { short8 v; unsigned short u[8]; } pk;
#pragma unroll
        for (int j = 0; j < 8; ++j) pk.u[j] = f2bf(rintf(fv[j] * 255.0f));
        int chunk = slot ^ (row & 7);
        *(short8*)&Ks[row * 64 + chunk * 8] = pk.v;
      }
      {
        const float* src = vh + (size_t)(jb * 64 + row) * HDc + slot * 8;
        float4 f0 = *(const float4*)src;
        float4 f1 = *(const float4*)(src + 4);
        float fv[8] = {f0.x, f0.y, f0.z, f0.w, f1.x, f1.y, f1.z, f1.w};
        union { short8 v; unsigned short u[8]; } pk;
#pragma unroll
        for (int j = 0; j < 8; ++j) pk.u[j] = f2bf(rintf(fv[j] * 255.0f));
        int chunk = slot ^ ((row >> 3) & 7);
        *(short8*)&Vs[row * 64 + chunk * 8] = pk.v;
      }
    }
    __syncthreads();

    // QK^T (exact integer)
    f32x4 accS[4];
#pragma unroll
    for (int nf = 0; nf < 4; ++nf) accS[nf] = (f32x4)(0.f);
#pragma unroll
    for (int ks = 0; ks < 2; ++ks) {
#pragma unroll
      for (int nf = 0; nf < 4; ++nf) {
        int kvr = nf * 16 + ln;
        short8 bk = *(const short8*)&Ks[kvr * 64 + ((ks * 32 + g * 8) ^ ((kvr & 7) << 3))];
        accS[nf] = __builtin_amdgcn_mfma_f32_16x16x32_bf16(qfrag[ks], bk, accS[nf], 0, 0, 0);
      }
    }

    // scale + causal mask
    float sv[4][4];
    if (jb == iq) {
      const int grow = iq * 64 + w * 16 + g * 4;
      const int gcol = jb * 64 + ln;
#pragma unroll
      for (int nf = 0; nf < 4; ++nf)
#pragma unroll
        for (int r = 0; r < 4; ++r)
          sv[nf][r] = (gcol + nf * 16 > grow + r) ? -1e30f : accS[nf][r] * SCALE;
    } else {
#pragma unroll
      for (int nf = 0; nf < 4; ++nf)
#pragma unroll
        for (int r = 0; r < 4; ++r) sv[nf][r] = accS[nf][r] * SCALE;
    }

    // online softmax: rows g*4+r, reduce across 16 ln lanes
    float mt[4];
#pragma unroll
    for (int r = 0; r < 4; ++r)
      mt[r] = fmaxf(fmaxf(sv[0][r], sv[1][r]), fmaxf(sv[2][r], sv[3][r]));
#pragma unroll
    for (int off = 1; off < 16; off <<= 1)
#pragma unroll
      for (int r = 0; r < 4; ++r) mt[r] = fmaxf(mt[r], __shfl_xor(mt[r], off));

    float pr[4][4], rs[4];
#pragma unroll
    for (int r = 0; r < 4; ++r) {
      float mn = fmaxf(m[r], mt[r]);
      float corr = __expf(m[r] - mn);
      m[r] = mn;
      l[r] *= corr;
#pragma unroll
      for (int nf = 0; nf < 4; ++nf) accO[nf][r] *= corr;
      float sum = 0.f;
#pragma unroll
      for (int nf = 0; nf < 4; ++nf) {
        float p = __expf(sv[nf][r] - mn);
        pr[nf][r] = p;
        sum += p;
      }
      rs[r] = sum;
    }
#pragma unroll
    for (int off = 1; off < 16; off <<= 1)
#pragma unroll
      for (int r = 0; r < 4; ++r) rs[r] += __shfl_xor(rs[r], off);
#pragma unroll
    for (int r = 0; r < 4; ++r) l[r] += rs[r];

    // write P hi/lo pairs to LDS (within-wave round trip; no barrier needed)
#pragma unroll
    for (int nf = 0; nf < 4; ++nf)
#pragma unroll
      for (int r = 0; r < 4; ++r) {
        unsigned short hi = f2bf(pr[nf][r]);
        unsigned short lo = f2bf(pr[nf][r] - bf2f(hi));
        int q = w * 16 + g * 4 + r;
        int kv = nf * 16 + ln;
        Pp[q * 64 + (kv ^ ((q & 7) << 3))] = (unsigned)hi | ((unsigned)lo << 16);
      }

    // PV
#pragma unroll
    for (int ks = 0; ks < 2; ++ks) {
      int qr = w * 16 + ln;
      int kv0 = ks * 32 + g * 8;
      int base = qr * 64 + (kv0 ^ ((qr & 7) << 3));
      short8 w0 = *(const short8*)&Pp[base];
      short8 w1 = *(const short8*)&Pp[base + 4];
      short8 pah = __builtin_shufflevector(w0, w1, 0, 2, 4, 6, 8, 10, 12, 14);
      short8 pal = __builtin_shufflevector(w0, w1, 1, 3, 5, 7, 9, 11, 13, 15);
      int xr = ((ks * 4 + g) & 7) << 3;
#pragma unroll
      for (int nf = 0; nf < 4; ++nf) {
        int dx = (nf * 16 + ln) ^ xr;
        union { short8 v; unsigned short u[8]; } bv;
#pragma unroll
        for (int j = 0; j < 8; ++j) bv.u[j] = Vs[(kv0 + j) * 64 + dx];
        accO[nf] = __builtin_amdgcn_mfma_f32_16x16x32_bf16(pah, bv.v, accO[nf], 0, 0, 0);
        accO[nf] = __builtin_amdgcn_mfma_f32_16x16x32_bf16(pal, bv.v, accO[nf], 0, 0, 0);
      }
    }
  }

  // normalize (V was integer-scaled: x255 cancels? No: P unscaled, V x255 -> /255 here via l? )
  // accO = sum p * (255*v) ; l = sum p ; out = accO / (255*l)
#pragma unroll
  for (int r = 0; r < 4; ++r) {
    float inv = 1.0f / (255.0f * l[r]);
    size_t row = (size_t)b * S_ + iq * 64 + w * 16 + g * 4 + r;
#pragma unroll
    for (int nf = 0; nf < 4; ++nf)
      aout[row * NXc + h * HDc + nf * 16 + ln] = accO[nf][r] * inv;
  }
}

// ---------------- host launcher ----------------
extern "C" void kernel_launch(void* const* d_in, const int* in_sizes, int n_in,
                              void* d_out, int out_size, void* d_ws, size_t ws_size,
                              hipStream_t stream) {
  const float* x      = (const float*)d_in[0];
  const float* W_attn = (const float*)d_in[1];
  const float* b_attn = (const float*)d_in[2];
  const float* W_proj = (const float*)d_in[3];
  const float* b_proj = (const float*)d_in[4];

  float* out = (float*)d_out;
  float* ws  = (float*)d_ws;
  if (ws_size < WS_FLOATS_NEEDED * sizeof(float)) return;

  float* a_out = out;
  float* k_out = out + (size_t)M_ * NXc;
  float* v_out = k_out + (size_t)M_ * NXc;

  unsigned short* ua  = (unsigned short*)(ws + UA_OFF_F);
  unsigned short* up  = (unsigned short*)(ws + UP_OFF_F);
  unsigned short* qbf = (unsigned short*)(ws + QBF_OFF_F);
  float* awsp = ws + AWS_OFF;
  unsigned int* sc = (unsigned int*)(ws + SC_OFF);

  hipMemsetAsync(sc, 0, 2 * sizeof(unsigned int), stream);

  k_maxtanh<<<256, 256, 0, stream>>>(W_attn, NXc * NQKV, sc);
  k_maxtanh<<<256, 256, 0, stream>>>(W_proj, NXc * NXc, sc + 1);

  k_quantw_t<<<dim3(NQKV / 64, NXc / 64), 256, 0, stream>>>(W_attn, ua, NXc, NQKV, sc);
  k_quantw_t<<<dim3(NXc / 64, NXc / 64), 256, 0, stream>>>(W_proj, up, NXc, NXc, sc + 1);

  k_gemm_mfma<1><<<dim3(NQKV / 128, M_ / 128), 256, 0, stream>>>(
      x, ua, b_attn, nullptr, qbf, k_out, v_out, M_, NQKV, NXc);

  k_attn_mfma<<<dim3(S_ / 64, H_, B_), 256, 0, stream>>>(qbf, k_out, v_out, awsp);

  k_gemm_mfma<0><<<dim3(NXc / 128, M_ / 128), 256, 0, stream>>>(
      awsp, up, b_proj, a_out, nullptr, nullptr, nullptr, M_, NXc, NXc);
}

// Round 4
// 233.531 us; speedup vs baseline: 4.2546x; 1.4097x over previous
//
#include <hip/hip_runtime.h>
#include <math.h>

#define B_   8
#define S_   1024
#define NXc  768
#define H_   12
#define HDc  64
#define M_   (B_*S_)        // 8192
#define NQKV (3*NXc)        // 2304

typedef __attribute__((ext_vector_type(8))) short short8;
typedef __attribute__((ext_vector_type(4))) float f32x4;

__device__ inline unsigned short f2bf(float f) {
  unsigned u = __float_as_uint(f);
  return (unsigned short)((u + 0x7fffu + ((u >> 16) & 1u)) >> 16);
}
__device__ inline float bf2f(unsigned short h) {
  return __uint_as_float(((unsigned)h) << 16);
}

// ---- workspace layout (floats) ----
static const size_t UA_OFF_F  = 0;                                   // bf16 Ut attn [NQKV][NXc]
static const size_t UA_F_CNT  = ((size_t)NQKV * NXc + 1) / 2;        // 884736
static const size_t UP_OFF_F  = UA_OFF_F + UA_F_CNT;                 // bf16 Ut proj [NXc][NXc]
static const size_t UP_F_CNT  = ((size_t)NXc * NXc + 1) / 2;         // 294912
static const size_t QBF_OFF_F = UP_OFF_F + UP_F_CNT;                 // bf16 int q [B,H,S,64]
static const size_t HALF_CNT  = ((size_t)M_ * NXc + 1) / 2;          // 3145728
static const size_t KBF_OFF_F = QBF_OFF_F + HALF_CNT;                // bf16 int k [B,H,S,64]
static const size_t VBT_OFF_F = KBF_OFF_F + HALF_CNT;                // bf16 int v^T [B,H,64,S]
static const size_t ABF_OFF_F = VBT_OFF_F + HALF_CNT;                // bf16 attn out [B,S,NX]
static const size_t SC_OFF    = ABF_OFF_F + HALF_CNT;
static const size_t WS_FLOATS_NEEDED = SC_OFF + 2;                   // ~13.8M floats (55MB)

// ---------------- max |tanh(w)| reduction ----------------
__global__ void k_maxtanh(const float* __restrict__ w, int n,
                          unsigned int* __restrict__ out) {
  float mx = 0.f;
  for (int i = blockIdx.x * blockDim.x + threadIdx.x; i < n;
       i += gridDim.x * blockDim.x)
    mx = fmaxf(mx, fabsf(tanhf(w[i])));
#pragma unroll
  for (int off = 32; off > 0; off >>= 1)
    mx = fmaxf(mx, __shfl_xor(mx, off));
  if ((threadIdx.x & 63) == 0)
    atomicMax(out, __float_as_uint(mx));   // floats >= 0: uint order == float order
}

// ---------------- DoReFa weight quant -> transposed exact-bf16 integer weights ----
__global__ __launch_bounds__(256) void k_quantw_t(
    const float* __restrict__ w, unsigned short* __restrict__ ut,
    int K, int N, const unsigned int* __restrict__ gmax_bits) {
  __shared__ unsigned short Ut[64][72];
  const float inv2m = 0.5f / __uint_as_float(*gmax_bits);
  const int k0 = blockIdx.y * 64, n0 = blockIdx.x * 64;
  const int t = threadIdx.x;
  const int r = t >> 4, c4 = (t & 15) * 4;
#pragma unroll
  for (int rr = 0; rr < 4; ++rr) {
    int row = rr * 16 + r;
    float4 f = *(const float4*)(w + (size_t)(k0 + row) * N + n0 + c4);
    float fv[4] = {f.x, f.y, f.z, f.w};
#pragma unroll
    for (int j = 0; j < 4; ++j) {
      float tq = tanhf(fv[j]) * inv2m + 0.5f;
      float u = 2.0f * rintf(tq * 255.0f) - 255.0f;
      Ut[c4 + j][row] = f2bf(u);
    }
  }
  __syncthreads();
#pragma unroll
  for (int rep = 0; rep < 2; ++rep) {
    int c = t + rep * 256;
    int n = c >> 3, slot = c & 7;
    short8 v = *(const short8*)&Ut[n][slot * 8];
    *(short8*)(ut + (size_t)(n0 + n) * K + k0 + slot * 8) = v;
  }
}

// ---------------- MFMA GEMM: C = (A * U^T)/255 + bias ----------------
// SPLIT=1: A fp32, on-the-fly hi/lo bf16 split, 2 MFMA per frag (exact to ~2^-16).
// SPLIT=0: A already bf16 (u16), 1 MFMA per frag.
// EPI 0: plain fp32 store. EPI 1: act-quant -> qbf/kbf/vbt (bf16 int) + k/v fp32 out.
template <int EPI, int SPLIT>
__global__ __launch_bounds__(256) void k_gemm_mfma(
    const float* __restrict__ A, const unsigned short* __restrict__ Abf,
    const unsigned short* __restrict__ Ut,
    const float* __restrict__ bias, float* __restrict__ Cplain,
    unsigned short* __restrict__ qbf, unsigned short* __restrict__ kbf,
    unsigned short* __restrict__ vbt,
    float* __restrict__ kq, float* __restrict__ vq,
    int M, int N, int K) {
  __shared__ short8 Ahi[4 * 128];
  __shared__ short8 Alo[4 * 128];   // unused when SPLIT==0
  __shared__ short8 Bsm[4 * 128];

  const int t = threadIdx.x;
  const int bm = blockIdx.y, bn = blockIdx.x;
  const int wave = t >> 6, lane = t & 63;
  const int wm = wave >> 1, wn = wave & 1;
  const int g = lane >> 4, ln = lane & 15;

  const float* Ab = A + (size_t)bm * 128 * K;
  const unsigned short* Abfb = Abf + (size_t)bm * 128 * K;
  const unsigned short* Bb = Ut + (size_t)bn * 128 * K;

  f32x4 acc[4][4];
#pragma unroll
  for (int i = 0; i < 4; ++i)
#pragma unroll
    for (int j = 0; j < 4; ++j) acc[i][j] = (f32x4)(0.f);

  for (int k0 = 0; k0 < K; k0 += 32) {
    __syncthreads();
    if (SPLIT == 1) {
#pragma unroll
      for (int rep = 0; rep < 2; ++rep) {
        int e = t + rep * 256;
        int slot = e & 3, mr = e >> 2;
        const float* src = Ab + (size_t)mr * K + k0 + slot * 8;
        float4 f0 = *(const float4*)(src);
        float4 f1 = *(const float4*)(src + 4);
        float fv[8] = {f0.x, f0.y, f0.z, f0.w, f1.x, f1.y, f1.z, f1.w};
        union { short8 v; unsigned short u[8]; } hi, lo;
#pragma unroll
        for (int j = 0; j < 8; ++j) {
          unsigned short hh = f2bf(fv[j]);
          hi.u[j] = hh;
          lo.u[j] = f2bf(fv[j] - bf2f(hh));
        }
        Ahi[slot * 128 + mr] = hi.v;
        Alo[slot * 128 + mr] = lo.v;
      }
    } else {
#pragma unroll
      for (int rep = 0; rep < 2; ++rep) {
        int e = t + rep * 256;
        int slot = e & 3, mr = e >> 2;
        Ahi[slot * 128 + mr] = *(const short8*)(Abfb + (size_t)mr * K + k0 + slot * 8);
      }
    }
#pragma unroll
    for (int rep = 0; rep < 2; ++rep) {
      int e = t + rep * 256;
      int slot = e & 3, nr = e >> 2;
      Bsm[slot * 128 + nr] = *(const short8*)(Bb + (size_t)nr * K + k0 + slot * 8);
    }
    __syncthreads();

    short8 bfrag[4];
#pragma unroll
    for (int nf = 0; nf < 4; ++nf)
      bfrag[nf] = Bsm[g * 128 + wn * 64 + nf * 16 + ln];
#pragma unroll
    for (int mf = 0; mf < 4; ++mf) {
      short8 ah = Ahi[g * 128 + wm * 64 + mf * 16 + ln];
#pragma unroll
      for (int nf = 0; nf < 4; ++nf)
        acc[mf][nf] = __builtin_amdgcn_mfma_f32_16x16x32_bf16(ah, bfrag[nf], acc[mf][nf], 0, 0, 0);
      if (SPLIT == 1) {
        short8 al = Alo[g * 128 + wm * 64 + mf * 16 + ln];
#pragma unroll
        for (int nf = 0; nf < 4; ++nf)
          acc[mf][nf] = __builtin_amdgcn_mfma_f32_16x16x32_bf16(al, bfrag[nf], acc[mf][nf], 0, 0, 0);
      }
    }
  }

  const float inv255 = 1.0f / 255.0f;
#pragma unroll
  for (int mf = 0; mf < 4; ++mf) {
    int row0 = bm * 128 + wm * 64 + mf * 16 + g * 4;
#pragma unroll
    for (int nf = 0; nf < 4; ++nf) {
      int col = bn * 128 + wn * 64 + nf * 16 + ln;
      float bv = bias[col];
#pragma unroll
      for (int r = 0; r < 4; ++r) {
        float x = acc[mf][nf][r] * inv255 + bv;
        int row = row0 + r;
        if (EPI == 0) {
          Cplain[(size_t)row * N + col] = x;
        } else {
          int part = col / NXc;
          int ff = col - part * NXc;
          int h = ff >> 6, d = ff & 63;
          int b = row >> 10, s = row & 1023;
          float y255 = rintf(fminf(fmaxf(x, 0.f), 1.f) * 255.0f);
          unsigned short ybf = f2bf(y255);
          size_t dst = (((size_t)b * H_ + h) * S_ + s) * HDc + d;
          if (part == 0) {
            qbf[dst] = ybf;
          } else if (part == 1) {
            kq[dst] = y255 * inv255;
            kbf[dst] = ybf;
          } else {
            vq[dst] = y255 * inv255;
            vbt[(((size_t)b * H_ + h) * HDc + d) * S_ + s] = ybf;   // transposed
          }
        }
      }
    }
  }
}

// ---------------- MFMA causal flash attention (paired q-blocks) ----------------
// grid (8, H, B), 256 thr (4 waves x 16 q-rows). WG p handles q-blocks {p, 15-p}
// -> exactly 17 kv-tiles per WG (perfect balance). All operands bf16 integers.
// QK^T exact (sums < 2^23). P bf16-only. V read from pre-transposed vbt.
__global__ __launch_bounds__(256) void k_attn_pair(
    const unsigned short* __restrict__ qbf, const unsigned short* __restrict__ kbf,
    const unsigned short* __restrict__ vbt, unsigned short* __restrict__ abf) {
  __shared__ __align__(16) unsigned short Ks[64 * 64];      // [kv][d] ^ ((kv&7)<<3)
  __shared__ __align__(16) unsigned short Vt[64 * 64];      // [d][kv] ^ ((d&7)<<3)
  __shared__ __align__(16) unsigned short Pp[4 * 16 * 64];  // per-wave [q][kv] ^ ((q&7)<<3)

  const int p = blockIdx.x, h = blockIdx.y, b = blockIdx.z;
  const size_t hoff = ((size_t)(b * H_ + h)) * S_ * HDc;  // same elem count for [s][d] and [d][s]
  const unsigned short* qh = qbf + hoff;
  const unsigned short* kh = kbf + hoff;
  const unsigned short* vh = vbt + hoff;

  const int t = threadIdx.x;
  const int w = t >> 6, lane = t & 63;
  const int g = lane >> 4, ln = lane & 15;

  const float SCALE = 1.0f / (255.0f * 255.0f * 8.0f);

  for (int ph = 0; ph < 2; ++ph) {
    const int iq = ph ? 15 - p : p;

    // Q fragments: rows iq*64 + w*16 + ln (integer-scaled bf16)
    const unsigned short* qr = qh + (size_t)(iq * 64 + w * 16 + ln) * HDc;
    short8 qfrag[2];
    qfrag[0] = *(const short8*)(qr + g * 8);
    qfrag[1] = *(const short8*)(qr + 32 + g * 8);

    float m[4], l[4];
    f32x4 accO[4];
#pragma unroll
    for (int r = 0; r < 4; ++r) { m[r] = -1e30f; l[r] = 0.f; }
#pragma unroll
    for (int nf = 0; nf < 4; ++nf) accO[nf] = (f32x4)(0.f);

    for (int jb = 0; jb <= iq; ++jb) {
      __syncthreads();   // previous tile's LDS reads complete
#pragma unroll
      for (int rep = 0; rep < 2; ++rep) {
        int e = t + rep * 256;
        int row = e >> 3, slot = e & 7;
        short8 kk = *(const short8*)(kh + (size_t)(jb * 64 + row) * HDc + slot * 8);
        *(short8*)&Ks[row * 64 + ((slot * 8) ^ ((row & 7) << 3))] = kk;
        short8 vv = *(const short8*)(vh + (size_t)row * S_ + jb * 64 + slot * 8);
        *(short8*)&Vt[row * 64 + ((slot * 8) ^ ((row & 7) << 3))] = vv;
      }
      __syncthreads();

      // QK^T (exact integer)
      f32x4 accS[4];
#pragma unroll
      for (int nf = 0; nf < 4; ++nf) accS[nf] = (f32x4)(0.f);
#pragma unroll
      for (int ks = 0; ks < 2; ++ks)
#pragma unroll
        for (int nf = 0; nf < 4; ++nf) {
          int kvr = nf * 16 + ln;
          short8 bk = *(const short8*)&Ks[kvr * 64 + ((ks * 32 + g * 8) ^ ((kvr & 7) << 3))];
          accS[nf] = __builtin_amdgcn_mfma_f32_16x16x32_bf16(qfrag[ks], bk, accS[nf], 0, 0, 0);
        }

      // scale + causal mask (rows g*4+r, cols nf*16+ln)
      float sv[4][4];
      if (jb == iq) {
        const int grow = iq * 64 + w * 16 + g * 4;
        const int gcol = jb * 64 + ln;
#pragma unroll
        for (int nf = 0; nf < 4; ++nf)
#pragma unroll
          for (int r = 0; r < 4; ++r)
            sv[nf][r] = (gcol + nf * 16 > grow + r) ? -1e30f : accS[nf][r] * SCALE;
      } else {
#pragma unroll
        for (int nf = 0; nf < 4; ++nf)
#pragma unroll
          for (int r = 0; r < 4; ++r) sv[nf][r] = accS[nf][r] * SCALE;
      }

      // online softmax (rows g*4+r shared by the 16 ln-lanes)
      float mt[4];
#pragma unroll
      for (int r = 0; r < 4; ++r)
        mt[r] = fmaxf(fmaxf(sv[0][r], sv[1][r]), fmaxf(sv[2][r], sv[3][r]));
#pragma unroll
      for (int off = 1; off < 16; off <<= 1)
#pragma unroll
        for (int r = 0; r < 4; ++r) mt[r] = fmaxf(mt[r], __shfl_xor(mt[r], off));

      float pr[4][4], rs[4];
#pragma unroll
      for (int r = 0; r < 4; ++r) {
        float mn = fmaxf(m[r], mt[r]);
        float corr = __expf(m[r] - mn);
        m[r] = mn;
        l[r] *= corr;
#pragma unroll
        for (int nf = 0; nf < 4; ++nf) accO[nf][r] *= corr;
        float sum = 0.f;
#pragma unroll
        for (int nf = 0; nf < 4; ++nf) {
          float pv = __expf(sv[nf][r] - mn);
          pr[nf][r] = pv;
          sum += pv;
        }
        rs[r] = sum;
      }
#pragma unroll
      for (int off = 1; off < 16; off <<= 1)
#pragma unroll
        for (int r = 0; r < 4; ++r) rs[r] += __shfl_xor(rs[r], off);
#pragma unroll
      for (int r = 0; r < 4; ++r) l[r] += rs[r];

      // P -> LDS (bf16, within-wave round trip, no barrier)
#pragma unroll
      for (int nf = 0; nf < 4; ++nf)
#pragma unroll
        for (int r = 0; r < 4; ++r) {
          int prow = g * 4 + r;
          Pp[w * 1024 + prow * 64 + ((nf * 16 + ln) ^ ((prow & 7) << 3))] = f2bf(pr[nf][r]);
        }

      // PV: accO[nf] += P(16x32) * V(32x16)
#pragma unroll
      for (int ks = 0; ks < 2; ++ks) {
        short8 pa = *(const short8*)&Pp[w * 1024 + ln * 64 + ((ks * 32 + g * 8) ^ ((ln & 7) << 3))];
#pragma unroll
        for (int nf = 0; nf < 4; ++nf) {
          int d = nf * 16 + ln;
          short8 bv = *(const short8*)&Vt[d * 64 + ((ks * 32 + g * 8) ^ ((d & 7) << 3))];
          accO[nf] = __builtin_amdgcn_mfma_f32_16x16x32_bf16(pa, bv, accO[nf], 0, 0, 0);
        }
      }
    }

    // write attn-out bf16 [B,S,NX]; accO rows q=g*4+r, cols d=nf*16+ln; V scaled x255
#pragma unroll
    for (int r = 0; r < 4; ++r) {
      float inv = 1.0f / (255.0f * l[r]);
      size_t row = (size_t)b * S_ + iq * 64 + w * 16 + g * 4 + r;
#pragma unroll
      for (int nf = 0; nf < 4; ++nf)
        abf[row * NXc + h * HDc + nf * 16 + ln] = f2bf(accO[nf][r] * inv);
    }
  }
}

// ---------------- host launcher ----------------
extern "C" void kernel_launch(void* const* d_in, const int* in_sizes, int n_in,
                              void* d_out, int out_size, void* d_ws, size_t ws_size,
                              hipStream_t stream) {
  const float* x      = (const float*)d_in[0];
  const float* W_attn = (const float*)d_in[1];
  const float* b_attn = (const float*)d_in[2];
  const float* W_proj = (const float*)d_in[3];
  const float* b_proj = (const float*)d_in[4];

  float* out = (float*)d_out;
  float* ws  = (float*)d_ws;
  if (ws_size < WS_FLOATS_NEEDED * sizeof(float)) return;

  float* a_out = out;                               // [B,S,NX]
  float* k_out = out + (size_t)M_ * NXc;            // present[0] = k  [B,H,S,hd]
  float* v_out = k_out + (size_t)M_ * NXc;          // present[1] = v

  unsigned short* ua  = (unsigned short*)(ws + UA_OFF_F);
  unsigned short* up  = (unsigned short*)(ws + UP_OFF_F);
  unsigned short* qbf = (unsigned short*)(ws + QBF_OFF_F);
  unsigned short* kbf = (unsigned short*)(ws + KBF_OFF_F);
  unsigned short* vbt = (unsigned short*)(ws + VBT_OFF_F);
  unsigned short* abf = (unsigned short*)(ws + ABF_OFF_F);
  unsigned int* sc = (unsigned int*)(ws + SC_OFF);

  hipMemsetAsync(sc, 0, 2 * sizeof(unsigned int), stream);

  k_maxtanh<<<256, 256, 0, stream>>>(W_attn, NXc * NQKV, sc);
  k_maxtanh<<<256, 256, 0, stream>>>(W_proj, NXc * NXc, sc + 1);

  k_quantw_t<<<dim3(NQKV / 64, NXc / 64), 256, 0, stream>>>(W_attn, ua, NXc, NQKV, sc);
  k_quantw_t<<<dim3(NXc / 64, NXc / 64), 256, 0, stream>>>(W_proj, up, NXc, NXc, sc + 1);

  // qkv = x @ wq_attn + b_attn (split-bf16 MFMA); emits bf16 q,k,v^T + fp32 present
  k_gemm_mfma<1, 1><<<dim3(NQKV / 128, M_ / 128), 256, 0, stream>>>(
      x, nullptr, ua, b_attn, nullptr, qbf, kbf, vbt, k_out, v_out, M_, NQKV, NXc);

  // causal attention (paired q-blocks, all-bf16)
  k_attn_pair<<<dim3(8, H_, B_), 256, 0, stream>>>(qbf, kbf, vbt, abf);

  // a = attn_out @ wq_proj + b_proj (bf16 A, single MFMA)
  k_gemm_mfma<0, 0><<<dim3(NXc / 128, M_ / 128), 256, 0, stream>>>(
      nullptr, abf, up, b_proj, a_out, nullptr, nullptr, nullptr, nullptr, nullptr,
      M_, NXc, NXc);
}